// Round 3
// baseline (141.595 us; speedup 1.0000x reference)
//
#include <hip/hip_runtime.h>
#include <math.h>
#include <limits.h>

#define NB1 8192     // sample histogram bins: float bits >> 19 (sign+exp+4 mantissa)
#define NB2 4096     // fine linear histogram bins over the band
#define TV 4         // float4 per array per thread per tile (16 elements)
#define GRID_MAIN 768  // 3 blocks/CU: fully resident, no block turnover

// Persistent device state. Invariant: all-zero at kernel_launch entry.
// Zero-initialized at module load; each launch restores zeros before finishing
// (sample_band's last block cleans g_H1/g_done1; final_kernel cleans g_hist2),
// so every call — including rocprof replays — starts from a clean state.
__device__ unsigned g_H1[NB1];
__device__ unsigned g_hist2[NB2];
__device__ float    g_band[2];
__device__ unsigned g_done1 = 0;

// loss = max(x,0) - x*t + log1p(exp(-|x|)) >= 0 ; p = sigmoid(x)
__device__ __forceinline__ void elem_f(float x, float t, float& l, float& p) {
    float e = __expf(-fabsf(x));
    l = fmaxf(x, 0.f) - x * t + __logf(1.f + e);
    float r = __builtin_amdgcn_rcpf(1.f + e);
    p = (x >= 0.f) ? r : e * r;
}

// ---------- k0: 1/16 chunked sample -> coarse bit-histogram ----------
// Fused: the LAST block also performs band selection and self-cleans g_H1.
__global__ __launch_bounds__(256) void sample_band_kernel(
    const float4* __restrict__ x4, const float4* __restrict__ t4,
    int n4, long long ks, long long M)
{
    __shared__ unsigned lh[NB1];   // 32 KB
    __shared__ int is_last;
    for (int i = threadIdx.x; i < NB1; i += 256) lh[i] = 0u;
    __syncthreads();

    int nth = gridDim.x * 256;
    int tid = blockIdx.x * 256 + threadIdx.x;
    int S4 = n4 >> 4;              // sampled float4 pairs
    int i0 = tid, i1 = tid + nth;

    float4 xa, ta, xb, tb;
    bool v0 = i0 < S4, v1 = i1 < S4;
    if (v0) {
        int f4 = ((i0 >> 6) << 10) + (i0 & 63);
        xa = x4[f4]; ta = t4[f4];
    }
    if (v1) {
        int f4 = ((i1 >> 6) << 10) + (i1 & 63);
        xb = x4[f4]; tb = t4[f4];
    }
    if (v0) {
        float xs[4] = {xa.x, xa.y, xa.z, xa.w};
        float ts[4] = {ta.x, ta.y, ta.z, ta.w};
        #pragma unroll
        for (int c = 0; c < 4; ++c) {
            float l, p; elem_f(xs[c], ts[c], l, p);
            atomicAdd(&lh[__float_as_uint(l) >> 19], 1u);
        }
    }
    if (v1) {
        float xs[4] = {xb.x, xb.y, xb.z, xb.w};
        float ts[4] = {tb.x, tb.y, tb.z, tb.w};
        #pragma unroll
        for (int c = 0; c < 4; ++c) {
            float l, p; elem_f(xs[c], ts[c], l, p);
            atomicAdd(&lh[__float_as_uint(l) >> 19], 1u);
        }
    }
    __syncthreads();
    for (int i = threadIdx.x; i < NB1; i += 256) {
        unsigned c = lh[i];
        if (c) atomicAdd(&g_H1[i], c);
    }
    __syncthreads();               // this block's H1 atomics are issued

    if (threadIdx.x == 0) {
        __threadfence();           // release
        is_last = (atomicAdd(&g_done1, 1u) == (unsigned)(gridDim.x - 1));
    }
    __syncthreads();
    if (!is_last) return;
    __threadfence();               // acquire: see all blocks' H1 atomics

    // ---- band selection: pick value band [vlo, vhi) containing kth value ----
    const uint4* hv = (const uint4*)g_H1;
    uint4* lv = (uint4*)lh;
    for (int i = threadIdx.x; i < NB1 / 4; i += 256) lv[i] = hv[i];
    __syncthreads();
    // self-clean persistent state for next call (H1 now staged in LDS)
    for (int i = threadIdx.x; i < NB1; i += 256) g_H1[i] = 0u;
    if (threadIdx.x == 0) g_done1 = 0u;

    if (threadIdx.x < 64) {
        int lane = threadIdx.x;
        int base = lane << 7;          // 128 bins per lane
        unsigned long long chunk = 0;
        for (int j = 0; j < 128; ++j) chunk += lh[base + j];
        unsigned long long s = chunk;  // inclusive suffix-scan across lanes
        #pragma unroll
        for (int off = 1; off < 64; off <<= 1) {
            unsigned long long v = __shfl_down(s, off);
            if (lane + off < 64) s += v;
        }
        unsigned long long above = s - chunk;

        int my_bhi = INT_MAX, my_blo = -1;
        unsigned long long c = above;
        for (int j = 127; j >= 0; --j) {
            unsigned h = lh[base + j];
            if ((long long)(c + h) < ks - M) my_bhi = base + j;
            if ((long long)c > ks + M && my_blo < 0) my_blo = base + j;
            c += h;
        }
        #pragma unroll
        for (int off = 32; off; off >>= 1) {
            int a = __shfl_down(my_bhi, off); my_bhi = min(my_bhi, a);
            int b = __shfl_down(my_blo, off); my_blo = max(my_blo, b);
        }
        if (lane == 0) {
            int bhi = (my_bhi == INT_MAX) ? (NB1 - 1) : my_bhi;
            int blo = my_blo;
            float vhi = __uint_as_float((unsigned)bhi << 19);
            float vlo = (blo < 0) ? 0.f : __uint_as_float((unsigned)(blo + 1) << 19);
            if (!(vlo < vhi)) vlo = 0.f;
            g_band[0] = vlo;
            g_band[1] = vhi;
        }
    }
}

__device__ __forceinline__ void process4(
    float4 xv, float4 tv, float vlo, float vhi, float scale,
    float& sp, float& spt, float& st, float& sgt, unsigned& cnt)
{
    float xs[4] = {xv.x, xv.y, xv.z, xv.w};
    float ts[4] = {tv.x, tv.y, tv.z, tv.w};
    #pragma unroll
    for (int c = 0; c < 4; ++c) {
        float l, p;
        elem_f(xs[c], ts[c], l, p);
        sp += p; spt += p * ts[c]; st += ts[c];
        if (l >= vhi) { cnt++; sgt += l; }
        else if (l >= vlo) {
            int b = min((int)((l - vlo) * scale), NB2 - 1);
            atomicAdd(&g_hist2[b], 1u);
        }
    }
}

// ---------- k1: single full pass, register double-buffered pipeline ----------
// Fixed 768-block grid (3 blocks/CU, all resident): each block walks tiles with
// ping-pong register buffers so tile r+1's 8 dwordx4 loads are in flight while
// tile r computes. Eliminates the block-turnover latency stalls of the old
// one-tile-per-block scheme (measured ~2.4 TB/s effective; floor is ~6 TB/s).
// Named A/B buffers, no runtime-indexed register arrays (scratch trap).
__global__ __launch_bounds__(256, 4) void main_kernel(
    const float4* __restrict__ x4, const float4* __restrict__ t4,
    float* __restrict__ q0, float* __restrict__ q1,
    float* __restrict__ q2, float* __restrict__ q3, unsigned* __restrict__ qc,
    const float* __restrict__ xg, const float* __restrict__ tg,
    int n, int n4)
{
    float vlo = g_band[0], vhi = g_band[1];
    float scale = (float)NB2 / (vhi - vlo);

    int ntiles = (n4 + 1023) >> 10;     // 1024 float4 per tile
    int fullTiles = n4 >> 10;           // tiles needing no bounds checks
    int tid = threadIdx.x;

    float sp = 0.f, spt = 0.f, st = 0.f, sgt = 0.f;
    unsigned cnt = 0;

    float4 xa[TV], ta[TV], xb[TV], tb[TV];

    auto LOAD = [&](int tile, float4 (&xd)[TV], float4 (&td)[TV]) {
        int base = (tile << 10) + tid;
        if (tile < fullTiles) {
            #pragma unroll
            for (int j = 0; j < TV; ++j) xd[j] = x4[base + j * 256];
            #pragma unroll
            for (int j = 0; j < TV; ++j) td[j] = t4[base + j * 256];
        } else {
            #pragma unroll
            for (int j = 0; j < TV; ++j) {
                int idx = base + j * 256;
                if (idx < n4) { xd[j] = x4[idx]; td[j] = t4[idx]; }
            }
        }
    };
    auto COMP = [&](int tile, float4 (&xd)[TV], float4 (&td)[TV]) {
        if (tile < fullTiles) {
            #pragma unroll
            for (int j = 0; j < TV; ++j)
                process4(xd[j], td[j], vlo, vhi, scale, sp, spt, st, sgt, cnt);
        } else {
            int base = (tile << 10) + tid;
            #pragma unroll
            for (int j = 0; j < TV; ++j) {
                int idx = base + j * 256;
                if (idx < n4)
                    process4(xd[j], td[j], vlo, vhi, scale, sp, spt, st, sgt, cnt);
            }
        }
    };

    int t0 = blockIdx.x;
    if (t0 < ntiles) {
        LOAD(t0, xa, ta);
        while (true) {
            int t1 = t0 + GRID_MAIN;
            if (t1 < ntiles) {
                LOAD(t1, xb, tb);          // prefetch B while A computes
                COMP(t0, xa, ta);
                int t2 = t1 + GRID_MAIN;
                if (t2 < ntiles) {
                    LOAD(t2, xa, ta);      // prefetch A while B computes
                    COMP(t1, xb, tb);
                    t0 = t2;
                    continue;
                }
                COMP(t1, xb, tb);
                break;
            }
            COMP(t0, xa, ta);
            break;
        }
    }

    // scalar tail (n % 4) on block 0
    int tail0 = n4 << 2;
    if (blockIdx.x == 0 && tid < (n - tail0)) {
        float x = xg[tail0 + tid], t = tg[tail0 + tid];
        float l, p;
        elem_f(x, t, l, p);
        sp += p; spt += p * t; st += t;
        if (l >= vhi) { cnt++; sgt += l; }
        else if (l >= vlo) {
            int b = min((int)((l - vlo) * scale), NB2 - 1);
            atomicAdd(&g_hist2[b], 1u);
        }
    }

    // wave -> block reduce, then ONE private slot write per block
    #pragma unroll
    for (int off = 32; off; off >>= 1) {
        sp  += __shfl_down(sp,  off);
        spt += __shfl_down(spt, off);
        st  += __shfl_down(st,  off);
        sgt += __shfl_down(sgt, off);
        cnt += __shfl_down(cnt, off);
    }
    __shared__ float    rs[4][4];
    __shared__ unsigned rc[4];
    int w = tid >> 6;
    if ((tid & 63) == 0) {
        rs[w][0] = sp; rs[w][1] = spt; rs[w][2] = st; rs[w][3] = sgt; rc[w] = cnt;
    }
    __syncthreads();
    if (tid == 0) {
        float a0 = 0, a1 = 0, a2 = 0, a3 = 0;
        unsigned c = 0;
        #pragma unroll
        for (int i = 0; i < 4; ++i) {
            a0 += rs[i][0]; a1 += rs[i][1]; a2 += rs[i][2]; a3 += rs[i][3]; c += rc[i];
        }
        q0[blockIdx.x] = a0; q1[blockIdx.x] = a1; q2[blockIdx.x] = a2;
        q3[blockIdx.x] = a3; qc[blockIdx.x] = c;
    }
}

// ---------- k2: reduce partials + resolve threshold bin + emit ----------
// Also self-cleans g_hist2 (values staged to LDS first).
__global__ __launch_bounds__(1024) void final_kernel(
    const float* __restrict__ q0, const float* __restrict__ q1,
    const float* __restrict__ q2, const float* __restrict__ q3,
    const unsigned* __restrict__ qc, int nblocks,
    float* __restrict__ out, long long k)
{
    __shared__ unsigned lh[NB2];        // 16 KB
    __shared__ double red[16][5];
    __shared__ double fin[5];

    for (int i = threadIdx.x; i < NB2; i += 1024) {
        lh[i] = g_hist2[i];
        g_hist2[i] = 0u;                // self-clean for next call
    }

    double a0 = 0, a1 = 0, a2 = 0, a3 = 0, a4 = 0;
    for (int i = threadIdx.x; i < nblocks; i += 1024) {
        a0 += (double)q0[i]; a1 += (double)q1[i]; a2 += (double)q2[i];
        a3 += (double)q3[i]; a4 += (double)qc[i];
    }
    #pragma unroll
    for (int off = 32; off; off >>= 1) {
        a0 += __shfl_down(a0, off); a1 += __shfl_down(a1, off);
        a2 += __shfl_down(a2, off); a3 += __shfl_down(a3, off);
        a4 += __shfl_down(a4, off);
    }
    int w = threadIdx.x >> 6;
    if ((threadIdx.x & 63) == 0) {
        red[w][0] = a0; red[w][1] = a1; red[w][2] = a2; red[w][3] = a3; red[w][4] = a4;
    }
    __syncthreads();
    if (threadIdx.x == 0) {
        double f0 = 0, f1 = 0, f2 = 0, f3 = 0, f4 = 0;
        for (int i = 0; i < 16; ++i) {
            f0 += red[i][0]; f1 += red[i][1]; f2 += red[i][2];
            f3 += red[i][3]; f4 += red[i][4];
        }
        fin[0] = f0; fin[1] = f1; fin[2] = f2; fin[3] = f3; fin[4] = f4;
    }
    __syncthreads();
    if (threadIdx.x >= 64) return;

    int lane = threadIdx.x;
    double SP = fin[0], SPT = fin[1], ST = fin[2], SGT = fin[3];
    long long CNT = (long long)fin[4];

    double vlo = (double)g_band[0], vhi = (double)g_band[1];
    double binw = (vhi - vlo) / NB2;
    long long k2 = k - CNT;

    int base = lane << 6;               // 64 bins per lane (LDS-resident)
    unsigned long long cchunk = 0;
    double wchunk = 0.0;
    for (int j = 0; j < 64; ++j) {
        unsigned h = lh[base + j];
        cchunk += h;
        wchunk += (double)h * (vlo + (base + j + 0.5) * binw);
    }
    unsigned long long cs = cchunk;
    double wsum = wchunk;
    #pragma unroll
    for (int off = 1; off < 64; off <<= 1) {
        unsigned long long cv = __shfl_down(cs, off);
        double wv = __shfl_down(wsum, off);
        if (lane + off < 64) { cs += cv; wsum += wv; }
    }
    unsigned long long total = __shfl(cs, 0);
    double wtotal = __shfl(wsum, 0);

    double I = SPT, U = SP + ST;
    double dice_part = 0.5 * (1.0 - (2.0 * I + 1e-6) / (U + 1e-6));

    if (k2 <= 0) {
        if (lane == 0) out[0] = (float)(SGT / (double)k + dice_part);
        return;
    }
    if ((unsigned long long)k2 > total) {
        if (lane == 0) {
            double sum_top = SGT + wtotal + (double)(k2 - (long long)total) * vlo;
            out[0] = (float)(sum_top / (double)k + dice_part);
        }
        return;
    }
    unsigned long long c = cs - cchunk;
    double wacc = wsum - wchunk;
    for (int j = 63; j >= 0; --j) {
        unsigned h = lh[base + j];
        double val = vlo + (base + j + 0.5) * binw;
        if (c < (unsigned long long)k2 && (unsigned long long)k2 <= c + h) {
            double sum_top = SGT + wacc + (double)((long long)k2 - (long long)c) * val;
            out[0] = (float)(sum_top / (double)k + dice_part);
        }
        c += h;
        wacc += (double)h * val;
    }
}

extern "C" void kernel_launch(void* const* d_in, const int* in_sizes, int n_in,
                              void* d_out, int out_size, void* d_ws, size_t ws_size,
                              hipStream_t stream)
{
    const float* x = (const float*)d_in[0];
    const float* t = (const float*)d_in[1];
    float* out = (float*)d_out;
    int n = in_sizes[0];
    int n4 = n >> 2;
    long long k = (long long)((double)n * 0.2);   // Python int() truncation
    if (k < 1) k = 1;

    long long S = (long long)(n4 >> 4) * 4;       // sampled element count
    long long ks = (S > 0) ? (long long)((double)k * (double)S / (double)n) : 0;
    long long M = 4096;                           // ~13 sigma sample-rank margin

    int grid = GRID_MAIN;                         // fixed resident grid

    int S4 = n4 >> 4;                             // sampled float4 pairs
    int sgrid = (S4 + 511) / 512;                 // 2 pairs per thread
    if (sgrid < 1) sgrid = 1;

    // workspace holds ONLY per-block partials (fully overwritten each call,
    // so harness poison is harmless and no memset dispatch is needed)
    unsigned char* ws = (unsigned char*)d_ws;
    size_t pstride = (((size_t)grid * 4) + 255) & ~(size_t)255;
    float*    q0 = (float*)(ws);
    float*    q1 = (float*)(ws + pstride);
    float*    q2 = (float*)(ws + 2 * pstride);
    float*    q3 = (float*)(ws + 3 * pstride);
    unsigned* qc = (unsigned*)(ws + 4 * pstride);

    sample_band_kernel<<<sgrid, 256, 0, stream>>>((const float4*)x, (const float4*)t,
                                                  n4, ks, M);
    main_kernel<<<grid, 256, 0, stream>>>((const float4*)x, (const float4*)t,
                                          q0, q1, q2, q3, qc, x, t, n, n4);
    final_kernel<<<1, 1024, 0, stream>>>(q0, q1, q2, q3, qc, grid, out, k);
}

// Round 4
// 137.583 us; speedup vs baseline: 1.0292x; 1.0292x over previous
//
#include <hip/hip_runtime.h>
#include <math.h>
#include <limits.h>

#define NB1 8192     // sample histogram bins: float bits >> 19 (sign+exp+4 mantissa)
#define NB2 4096     // fine linear histogram bins over the band
#define VEC 4        // float4 per array per thread in main kernel (16 elements)
#define NREP 4       // replicated global fine-hist copies (blockIdx & 3)

// Persistent device state. Invariant: all-zero at kernel_launch entry.
// Zero-initialized at module load; each launch restores zeros before finishing
// (sample_band's last block cleans g_H1/g_done1; final_kernel cleans g_hist2),
// so every call — including rocprof replays — starts from a clean state.
__device__ unsigned g_H1[NB1];
__device__ unsigned g_hist2[NREP * NB2];   // 64 KB, 4 replicated copies
__device__ float    g_band[2];
__device__ unsigned g_done1 = 0;

// loss = max(x,0) - x*t + log1p(exp(-|x|)) >= 0 ; p = sigmoid(x)
__device__ __forceinline__ void elem_f(float x, float t, float& l, float& p) {
    float e = __expf(-fabsf(x));
    l = fmaxf(x, 0.f) - x * t + __logf(1.f + e);
    float r = __builtin_amdgcn_rcpf(1.f + e);
    p = (x >= 0.f) ? r : e * r;
}

// ---------- k0: 1/16 chunked sample -> coarse bit-histogram ----------
// Fused: the LAST block also performs band selection and self-cleans g_H1.
__global__ __launch_bounds__(256) void sample_band_kernel(
    const float4* __restrict__ x4, const float4* __restrict__ t4,
    int n4, long long ks, long long M)
{
    __shared__ unsigned lh[NB1];   // 32 KB
    __shared__ int is_last;
    for (int i = threadIdx.x; i < NB1; i += 256) lh[i] = 0u;
    __syncthreads();

    int nth = gridDim.x * 256;
    int tid = blockIdx.x * 256 + threadIdx.x;
    int S4 = n4 >> 4;              // sampled float4 pairs
    int i0 = tid, i1 = tid + nth;

    float4 xa, ta, xb, tb;
    bool v0 = i0 < S4, v1 = i1 < S4;
    if (v0) {
        int f4 = ((i0 >> 6) << 10) + (i0 & 63);
        xa = x4[f4]; ta = t4[f4];
    }
    if (v1) {
        int f4 = ((i1 >> 6) << 10) + (i1 & 63);
        xb = x4[f4]; tb = t4[f4];
    }
    if (v0) {
        float xs[4] = {xa.x, xa.y, xa.z, xa.w};
        float ts[4] = {ta.x, ta.y, ta.z, ta.w};
        #pragma unroll
        for (int c = 0; c < 4; ++c) {
            float l, p; elem_f(xs[c], ts[c], l, p);
            atomicAdd(&lh[__float_as_uint(l) >> 19], 1u);
        }
    }
    if (v1) {
        float xs[4] = {xb.x, xb.y, xb.z, xb.w};
        float ts[4] = {tb.x, tb.y, tb.z, tb.w};
        #pragma unroll
        for (int c = 0; c < 4; ++c) {
            float l, p; elem_f(xs[c], ts[c], l, p);
            atomicAdd(&lh[__float_as_uint(l) >> 19], 1u);
        }
    }
    __syncthreads();
    for (int i = threadIdx.x; i < NB1; i += 256) {
        unsigned c = lh[i];
        if (c) atomicAdd(&g_H1[i], c);
    }
    __syncthreads();               // this block's H1 atomics are issued

    if (threadIdx.x == 0) {
        __threadfence();           // release
        is_last = (atomicAdd(&g_done1, 1u) == (unsigned)(gridDim.x - 1));
    }
    __syncthreads();
    if (!is_last) return;
    __threadfence();               // acquire: see all blocks' H1 atomics

    // ---- band selection: pick value band [vlo, vhi) containing kth value ----
    const uint4* hv = (const uint4*)g_H1;
    uint4* lv = (uint4*)lh;
    for (int i = threadIdx.x; i < NB1 / 4; i += 256) lv[i] = hv[i];
    __syncthreads();
    // self-clean persistent state for next call (H1 now staged in LDS)
    for (int i = threadIdx.x; i < NB1; i += 256) g_H1[i] = 0u;
    if (threadIdx.x == 0) g_done1 = 0u;

    if (threadIdx.x < 64) {
        int lane = threadIdx.x;
        int base = lane << 7;          // 128 bins per lane
        unsigned long long chunk = 0;
        for (int j = 0; j < 128; ++j) chunk += lh[base + j];
        unsigned long long s = chunk;  // inclusive suffix-scan across lanes
        #pragma unroll
        for (int off = 1; off < 64; off <<= 1) {
            unsigned long long v = __shfl_down(s, off);
            if (lane + off < 64) s += v;
        }
        unsigned long long above = s - chunk;

        int my_bhi = INT_MAX, my_blo = -1;
        unsigned long long c = above;
        for (int j = 127; j >= 0; --j) {
            unsigned h = lh[base + j];
            if ((long long)(c + h) < ks - M) my_bhi = base + j;
            if ((long long)c > ks + M && my_blo < 0) my_blo = base + j;
            c += h;
        }
        #pragma unroll
        for (int off = 32; off; off >>= 1) {
            int a = __shfl_down(my_bhi, off); my_bhi = min(my_bhi, a);
            int b = __shfl_down(my_blo, off); my_blo = max(my_blo, b);
        }
        if (lane == 0) {
            int bhi = (my_bhi == INT_MAX) ? (NB1 - 1) : my_bhi;
            int blo = my_blo;
            float vhi = __uint_as_float((unsigned)bhi << 19);
            float vlo = (blo < 0) ? 0.f : __uint_as_float((unsigned)(blo + 1) << 19);
            if (!(vlo < vhi)) vlo = 0.f;
            g_band[0] = vlo;
            g_band[1] = vhi;
        }
    }
}

// Element path: LDS histogram (DS pipe — keeps the vmcnt queue pure loads, so
// prior atomics can never delay load retirement; that coupling was main's
// 2.1 TB/s ceiling in R0-R3).
__device__ __forceinline__ void process4(
    float4 xv, float4 tv, float vlo, float vhi, float scale,
    float& sp, float& spt, float& st, float& sgt, unsigned& cnt,
    unsigned (&lhist)[NB2])
{
    float xs[4] = {xv.x, xv.y, xv.z, xv.w};
    float ts[4] = {tv.x, tv.y, tv.z, tv.w};
    #pragma unroll
    for (int c = 0; c < 4; ++c) {
        float l, p;
        elem_f(xs[c], ts[c], l, p);
        sp += p; spt += p * ts[c]; st += ts[c];
        if (l >= vhi) { cnt++; sgt += l; }
        else if (l >= vlo) {
            int b = min((int)((l - vlo) * scale), NB2 - 1);
            atomicAdd(&lhist[b], 1u);
        }
    }
}

// ---------- k1: single full pass; per-block partials to private slots ----------
// (256,4): 128-VGPR budget so all 2*VEC dwordx4 loads issue before first use.
// Fine-hist via LDS privatization + end-of-block flush to one of NREP global
// copies: removes ~2.4M sparse global_atomic instrs from the main loop's
// vmcnt stream (they serialized load completion in-order).
__global__ __launch_bounds__(256, 4) void main_kernel(
    const float4* __restrict__ x4, const float4* __restrict__ t4,
    float* __restrict__ q0, float* __restrict__ q1,
    float* __restrict__ q2, float* __restrict__ q3, unsigned* __restrict__ qc,
    const float* __restrict__ xg, const float* __restrict__ tg,
    int n, int n4)
{
    __shared__ unsigned lhist[NB2];    // 16 KB private fine-hist
    for (int i = threadIdx.x; i < NB2; i += 256) lhist[i] = 0u;
    __syncthreads();

    float vlo = g_band[0], vhi = g_band[1];
    float scale = (float)NB2 / (vhi - vlo);

    int base = blockIdx.x * (256 * VEC) + threadIdx.x;
    float sp = 0.f, spt = 0.f, st = 0.f, sgt = 0.f;
    unsigned cnt = 0;

    bool full = (blockIdx.x + 1) * (256 * VEC) <= n4;   // block-uniform
    if (full) {
        float4 xv[VEC], tv[VEC];
        #pragma unroll
        for (int j = 0; j < VEC; ++j) xv[j] = x4[base + j * 256];
        #pragma unroll
        for (int j = 0; j < VEC; ++j) tv[j] = t4[base + j * 256];
        #pragma unroll
        for (int j = 0; j < VEC; ++j)
            process4(xv[j], tv[j], vlo, vhi, scale, sp, spt, st, sgt, cnt, lhist);
    } else {
        for (int j = 0; j < VEC; ++j) {
            int idx = base + j * 256;
            if (idx < n4)
                process4(x4[idx], t4[idx], vlo, vhi, scale, sp, spt, st, sgt, cnt, lhist);
        }
    }
    // scalar tail (n % 4) on block 0
    int tail0 = n4 << 2;
    if (blockIdx.x == 0 && threadIdx.x < (n - tail0)) {
        float x = xg[tail0 + threadIdx.x], t = tg[tail0 + threadIdx.x];
        float l, p;
        elem_f(x, t, l, p);
        sp += p; spt += p * t; st += t;
        if (l >= vhi) { cnt++; sgt += l; }
        else if (l >= vlo) {
            int b = min((int)((l - vlo) * scale), NB2 - 1);
            atomicAdd(&lhist[b], 1u);
        }
    }

    // flush private fine-hist: batched full-wave atomics, NREP-way replicated
    __syncthreads();
    {
        unsigned* dst = &g_hist2[(blockIdx.x & (NREP - 1)) * NB2];
        for (int i = threadIdx.x; i < NB2; i += 256) {
            unsigned c = lhist[i];
            if (c) atomicAdd(&dst[i], c);
        }
    }

    // wave -> block reduce, then ONE private slot write per block
    #pragma unroll
    for (int off = 32; off; off >>= 1) {
        sp  += __shfl_down(sp,  off);
        spt += __shfl_down(spt, off);
        st  += __shfl_down(st,  off);
        sgt += __shfl_down(sgt, off);
        cnt += __shfl_down(cnt, off);
    }
    __shared__ float    rs[4][4];
    __shared__ unsigned rc[4];
    int w = threadIdx.x >> 6;
    if ((threadIdx.x & 63) == 0) {
        rs[w][0] = sp; rs[w][1] = spt; rs[w][2] = st; rs[w][3] = sgt; rc[w] = cnt;
    }
    __syncthreads();
    if (threadIdx.x == 0) {
        float a0 = 0, a1 = 0, a2 = 0, a3 = 0;
        unsigned c = 0;
        #pragma unroll
        for (int i = 0; i < 4; ++i) {
            a0 += rs[i][0]; a1 += rs[i][1]; a2 += rs[i][2]; a3 += rs[i][3]; c += rc[i];
        }
        q0[blockIdx.x] = a0; q1[blockIdx.x] = a1; q2[blockIdx.x] = a2;
        q3[blockIdx.x] = a3; qc[blockIdx.x] = c;
    }
}

// ---------- k2: reduce partials + resolve threshold bin + emit ----------
// Merges the NREP hist copies; self-cleans all of g_hist2 (staged to LDS first).
__global__ __launch_bounds__(1024) void final_kernel(
    const float* __restrict__ q0, const float* __restrict__ q1,
    const float* __restrict__ q2, const float* __restrict__ q3,
    const unsigned* __restrict__ qc, int nblocks,
    float* __restrict__ out, long long k)
{
    __shared__ unsigned lh[NB2];        // 16 KB
    __shared__ double red[16][5];
    __shared__ double fin[5];

    for (int i = threadIdx.x; i < NB2; i += 1024) {
        unsigned s = 0;
        #pragma unroll
        for (int r = 0; r < NREP; ++r) {
            s += g_hist2[r * NB2 + i];
            g_hist2[r * NB2 + i] = 0u;  // self-clean for next call
        }
        lh[i] = s;
    }

    double a0 = 0, a1 = 0, a2 = 0, a3 = 0, a4 = 0;
    for (int i = threadIdx.x; i < nblocks; i += 1024) {
        a0 += (double)q0[i]; a1 += (double)q1[i]; a2 += (double)q2[i];
        a3 += (double)q3[i]; a4 += (double)qc[i];
    }
    #pragma unroll
    for (int off = 32; off; off >>= 1) {
        a0 += __shfl_down(a0, off); a1 += __shfl_down(a1, off);
        a2 += __shfl_down(a2, off); a3 += __shfl_down(a3, off);
        a4 += __shfl_down(a4, off);
    }
    int w = threadIdx.x >> 6;
    if ((threadIdx.x & 63) == 0) {
        red[w][0] = a0; red[w][1] = a1; red[w][2] = a2; red[w][3] = a3; red[w][4] = a4;
    }
    __syncthreads();
    if (threadIdx.x == 0) {
        double f0 = 0, f1 = 0, f2 = 0, f3 = 0, f4 = 0;
        for (int i = 0; i < 16; ++i) {
            f0 += red[i][0]; f1 += red[i][1]; f2 += red[i][2];
            f3 += red[i][3]; f4 += red[i][4];
        }
        fin[0] = f0; fin[1] = f1; fin[2] = f2; fin[3] = f3; fin[4] = f4;
    }
    __syncthreads();
    if (threadIdx.x >= 64) return;

    int lane = threadIdx.x;
    double SP = fin[0], SPT = fin[1], ST = fin[2], SGT = fin[3];
    long long CNT = (long long)fin[4];

    double vlo = (double)g_band[0], vhi = (double)g_band[1];
    double binw = (vhi - vlo) / NB2;
    long long k2 = k - CNT;

    int base = lane << 6;               // 64 bins per lane (LDS-resident)
    unsigned long long cchunk = 0;
    double wchunk = 0.0;
    for (int j = 0; j < 64; ++j) {
        unsigned h = lh[base + j];
        cchunk += h;
        wchunk += (double)h * (vlo + (base + j + 0.5) * binw);
    }
    unsigned long long cs = cchunk;
    double wsum = wchunk;
    #pragma unroll
    for (int off = 1; off < 64; off <<= 1) {
        unsigned long long cv = __shfl_down(cs, off);
        double wv = __shfl_down(wsum, off);
        if (lane + off < 64) { cs += cv; wsum += wv; }
    }
    unsigned long long total = __shfl(cs, 0);
    double wtotal = __shfl(wsum, 0);

    double I = SPT, U = SP + ST;
    double dice_part = 0.5 * (1.0 - (2.0 * I + 1e-6) / (U + 1e-6));

    if (k2 <= 0) {
        if (lane == 0) out[0] = (float)(SGT / (double)k + dice_part);
        return;
    }
    if ((unsigned long long)k2 > total) {
        if (lane == 0) {
            double sum_top = SGT + wtotal + (double)(k2 - (long long)total) * vlo;
            out[0] = (float)(sum_top / (double)k + dice_part);
        }
        return;
    }
    unsigned long long c = cs - cchunk;
    double wacc = wsum - wchunk;
    for (int j = 63; j >= 0; --j) {
        unsigned h = lh[base + j];
        double val = vlo + (base + j + 0.5) * binw;
        if (c < (unsigned long long)k2 && (unsigned long long)k2 <= c + h) {
            double sum_top = SGT + wacc + (double)((long long)k2 - (long long)c) * val;
            out[0] = (float)(sum_top / (double)k + dice_part);
        }
        c += h;
        wacc += (double)h * val;
    }
}

extern "C" void kernel_launch(void* const* d_in, const int* in_sizes, int n_in,
                              void* d_out, int out_size, void* d_ws, size_t ws_size,
                              hipStream_t stream)
{
    const float* x = (const float*)d_in[0];
    const float* t = (const float*)d_in[1];
    float* out = (float*)d_out;
    int n = in_sizes[0];
    int n4 = n >> 2;
    long long k = (long long)((double)n * 0.2);   // Python int() truncation
    if (k < 1) k = 1;

    long long S = (long long)(n4 >> 4) * 4;       // sampled element count
    long long ks = (S > 0) ? (long long)((double)k * (double)S / (double)n) : 0;
    long long M = 4096;                           // ~13 sigma sample-rank margin

    int tilesz = 256 * VEC;                       // float4 per tile
    int grid = (n4 + tilesz - 1) / tilesz;
    if (grid < 1) grid = 1;

    int S4 = n4 >> 4;                             // sampled float4 pairs
    int sgrid = (S4 + 511) / 512;                 // 2 pairs per thread
    if (sgrid < 1) sgrid = 1;

    // workspace holds ONLY per-block partials (fully overwritten each call,
    // so harness poison is harmless and no memset dispatch is needed)
    unsigned char* ws = (unsigned char*)d_ws;
    size_t pstride = (((size_t)grid * 4) + 255) & ~(size_t)255;
    float*    q0 = (float*)(ws);
    float*    q1 = (float*)(ws + pstride);
    float*    q2 = (float*)(ws + 2 * pstride);
    float*    q3 = (float*)(ws + 3 * pstride);
    unsigned* qc = (unsigned*)(ws + 4 * pstride);

    sample_band_kernel<<<sgrid, 256, 0, stream>>>((const float4*)x, (const float4*)t,
                                                  n4, ks, M);
    main_kernel<<<grid, 256, 0, stream>>>((const float4*)x, (const float4*)t,
                                          q0, q1, q2, q3, qc, x, t, n, n4);
    final_kernel<<<1, 1024, 0, stream>>>(q0, q1, q2, q3, qc, grid, out, k);
}